// Round 1
// baseline (368.146 us; speedup 1.0000x reference)
//
#include <hip/hip_runtime.h>

typedef unsigned short u16;
typedef unsigned int u32;
typedef __attribute__((ext_vector_type(4))) float f32x4;
typedef __attribute__((ext_vector_type(8))) u16 u16x8;
typedef __attribute__((ext_vector_type(4))) u16 u16x4;
typedef __attribute__((ext_vector_type(8))) __bf16 bf16x8;

#define IN_F 512
#define OUT_F 512
#define KTOT 4608   // 512 (silu) + 512*8 (spline bases)
#define BATCH 16384
#define BM 128
#define BN 128
#define BK 64
#define LDSS 72     // padded LDS row stride in u16 (144B = 9*16B: aligned, ~2-way banks)
#define NKT (KTOT / BK)

__device__ __forceinline__ u16 f2bf(float f) {
  u32 u = __float_as_uint(f);
  u32 r = (u + 0x7FFFu + ((u >> 16) & 1u)) >> 16;  // round-to-nearest-even
  return (u16)r;
}

__device__ __forceinline__ float siluf(float v) {
  return v / (1.0f + __expf(-v));
}

// order-3 B-spline bases (8 of them) at x, exact replica of the reference recursion.
__device__ __forceinline__ void bases8(float x, const float g[12],
                                       const float inv1[11], const float inv2[10],
                                       const float inv3[9], float out[8]) {
  float b[11];
#pragma unroll
  for (int t = 0; t < 11; ++t)
    b[t] = (x >= g[t] && x < g[t + 1]) ? 1.0f : 0.0f;
  float c[10];
#pragma unroll
  for (int t = 0; t < 10; ++t)
    c[t] = (x - g[t]) * inv1[t] * b[t] + (g[t + 2] - x) * inv1[t + 1] * b[t + 1];
  float d[9];
#pragma unroll
  for (int t = 0; t < 9; ++t)
    d[t] = (x - g[t]) * inv2[t] * c[t] + (g[t + 3] - x) * inv2[t + 1] * c[t + 1];
#pragma unroll
  for (int t = 0; t < 8; ++t)
    out[t] = (x - g[t]) * inv3[t] * d[t] + (g[t + 4] - x) * inv3[t + 1] * d[t + 1];
}

// Build combined weight matrix Wc[o][k] (bf16): k<512 -> base_weight, else spline_weight*scaler
__global__ __launch_bounds__(256) void kan_prep_w(const float* __restrict__ bw,
                                                  const float* __restrict__ sw,
                                                  const float* __restrict__ ss,
                                                  u16* __restrict__ Wc) {
  const int k = blockIdx.x * 256 + threadIdx.x;  // 0..4607
  const int o = blockIdx.y;                      // 0..511
  float v;
  if (k < 512) {
    v = bw[o * 512 + k];
  } else {
    const int rel = k - 512;                     // i*8 + j
    v = sw[o * 4096 + rel] * ss[o * 512 + (rel >> 3)];
  }
  Wc[(size_t)o * KTOT + k] = f2bf(v);
}

__global__ __launch_bounds__(256) void kan_gemm(const float* __restrict__ x,
                                                const u16* __restrict__ Wc,
                                                const float* __restrict__ grid,
                                                float* __restrict__ out) {
  __shared__ u16 As[BM * LDSS];
  __shared__ u16 Bs[BN * LDSS];
  const int tid = threadIdx.x;
  const int n0 = blockIdx.x * BN;
  const int m0 = blockIdx.y * BM;

  // knot vector + reciprocal spacings (wave-uniform, hoisted)
  float g[12], inv1[11], inv2[10], inv3[9];
#pragma unroll
  for (int t = 0; t < 12; ++t) g[t] = grid[t];
#pragma unroll
  for (int t = 0; t < 11; ++t) inv1[t] = 1.0f / (g[t + 1] - g[t]);
#pragma unroll
  for (int t = 0; t < 10; ++t) inv2[t] = 1.0f / (g[t + 2] - g[t]);
#pragma unroll
  for (int t = 0; t < 9; ++t)  inv3[t] = 1.0f / (g[t + 3] - g[t]);

  const int lane = tid & 63;
  const int wave = tid >> 6;
  const int wr = wave >> 1;   // wave row 0..1 (64-row sub-tile)
  const int wcn = wave & 1;   // wave col 0..1 (64-col sub-tile)
  const int lr = lane & 15;
  const int lk = lane >> 4;   // 0..3

  const int srow = tid >> 1;  // staging row 0..127
  const int shalf = tid & 1;  // staging half (32 cols each)

  f32x4 acc[4][4];
  const f32x4 zero = {0.0f, 0.0f, 0.0f, 0.0f};
#pragma unroll
  for (int m = 0; m < 4; ++m)
#pragma unroll
    for (int n = 0; n < 4; ++n) acc[m][n] = zero;

  for (int kt = 0; kt < NKT; ++kt) {
    const int k0 = kt * BK;
    __syncthreads();
    // ---- stage B (weights, bf16 from ws), reg-staged
    {
      const u16* src = &Wc[(size_t)(n0 + srow) * KTOT + k0 + shalf * 32];
      u16* dst = &Bs[srow * LDSS + shalf * 32];
#pragma unroll
      for (int q = 0; q < 4; ++q)
        *(u16x8*)&dst[q * 8] = *(const u16x8*)&src[q * 8];
    }
    // ---- stage A (computed on the fly from x)
    if (k0 < 512) {
      // silu region: A[r][c] = silu(x[m0+r][k0+c])
      const float* xs = &x[(size_t)(m0 + srow) * IN_F + k0 + shalf * 32];
      u16* dst = &As[srow * LDSS + shalf * 32];
#pragma unroll
      for (int q = 0; q < 8; ++q) {
        f32x4 v = *(const f32x4*)&xs[q * 4];
        u16x4 p;
#pragma unroll
        for (int e = 0; e < 4; ++e) p[e] = f2bf(siluf(v[e]));
        *(u16x4*)&dst[q * 4] = p;
      }
    } else {
      // spline region: 8 x-columns -> 8 bases each
      const int i0 = (k0 - 512) >> 3;
      f32x4 xv = *(const f32x4*)&x[(size_t)(m0 + srow) * IN_F + i0 + shalf * 4];
      u16* dst = &As[srow * LDSS + shalf * 32];
#pragma unroll
      for (int q = 0; q < 4; ++q) {
        float e8[8];
        bases8(xv[q], g, inv1, inv2, inv3, e8);
        u16x8 p;
#pragma unroll
        for (int e = 0; e < 8; ++e) p[e] = f2bf(e8[e]);
        *(u16x8*)&dst[q * 8] = p;
      }
    }
    __syncthreads();
    // ---- MFMA compute: 2 k-substeps of 32
#pragma unroll
    for (int s = 0; s < 2; ++s) {
      bf16x8 a[4], b[4];
#pragma unroll
      for (int m = 0; m < 4; ++m)
        a[m] = *(const bf16x8*)&As[(wr * 64 + m * 16 + lr) * LDSS + s * 32 + lk * 8];
#pragma unroll
      for (int n = 0; n < 4; ++n)
        b[n] = *(const bf16x8*)&Bs[(wcn * 64 + n * 16 + lr) * LDSS + s * 32 + lk * 8];
#pragma unroll
      for (int m = 0; m < 4; ++m)
#pragma unroll
        for (int n = 0; n < 4; ++n)
          acc[m][n] = __builtin_amdgcn_mfma_f32_16x16x32_bf16(a[m], b[n], acc[m][n], 0, 0, 0);
    }
  }

  // epilogue: C/D layout col=lane&15, row=(lane>>4)*4+j (m89-verified)
#pragma unroll
  for (int m = 0; m < 4; ++m)
#pragma unroll
    for (int n = 0; n < 4; ++n)
#pragma unroll
      for (int j = 0; j < 4; ++j)
        out[(size_t)(m0 + wr * 64 + m * 16 + lk * 4 + j) * OUT_F
            + n0 + wcn * 64 + n * 16 + lr] = acc[m][n][j];
}

extern "C" void kernel_launch(void* const* d_in, const int* in_sizes, int n_in,
                              void* d_out, int out_size, void* d_ws, size_t ws_size,
                              hipStream_t stream) {
  const float* x    = (const float*)d_in[0];
  const float* bw   = (const float*)d_in[1];
  const float* sw   = (const float*)d_in[2];
  const float* ss   = (const float*)d_in[3];
  const float* grid = (const float*)d_in[4];
  u16* Wc = (u16*)d_ws;  // 512*4608*2 = 4.72 MB

  kan_prep_w<<<dim3(KTOT / 256, OUT_F), 256, 0, stream>>>(bw, sw, ss, Wc);
  kan_gemm<<<dim3(OUT_F / BN, BATCH / BM), 256, 0, stream>>>(
      x, Wc, grid, (float*)d_out);
}

// Round 2
// 275.740 us; speedup vs baseline: 1.3351x; 1.3351x over previous
//
#include <hip/hip_runtime.h>

typedef unsigned short u16;
typedef unsigned int u32;
typedef unsigned long long u64;
typedef __attribute__((ext_vector_type(4))) float f32x4;
typedef __attribute__((ext_vector_type(8))) u16 u16x8;
typedef __attribute__((ext_vector_type(8))) __bf16 bf16x8;

#define IN_F 512
#define OUT_F 512
#define KTOT 4608   // 512 silu + 512*8 spline bases
#define BM 128
#define BN 256
#define BK 64
#define LDSS 72     // padded LDS row stride in u16 (144B = 9*16B)
#define NKT 72
#define NSIL 8      // first 8 k-tiles are the silu region

__device__ __forceinline__ u16 f2bf(float f) {
  u32 u = __float_as_uint(f);
  return (u16)((u + 0x7FFFu + ((u >> 16) & 1u)) >> 16);  // RNE
}
__device__ __forceinline__ float siluf(float v) { return v / (1.0f + __expf(-v)); }

// Uniform-knot cubic B-spline: 8 bf16 bases of x packed into (lo,hi) 128-bit.
// u = (x+2.2)/0.4; cell c = floor(u); 4 cardinal weights at t = c-3..c.
__device__ __forceinline__ void spline8(float xv, u64& lo, u64& hi) {
  float u = fmaf(xv, 2.5f, 5.5f);
  float cf = floorf(u);
  float f = u - cf;
  int c = (int)cf;
  bool valid = (u >= 0.0f) && (u < 11.0f);
  c = c < 0 ? 0 : (c > 10 ? 10 : c);
  float f2 = f * f, f3 = f2 * f;
  float v1 = 1.0f - f;
  float w0 = v1 * v1 * v1 * (1.0f / 6.0f);
  float w1 = 0.5f * f3 - f2 + (2.0f / 3.0f);
  float w2 = -0.5f * f3 + 0.5f * f2 + 0.5f * f + (1.0f / 6.0f);
  float w3 = f3 * (1.0f / 6.0f);
  u64 W = (u64)f2bf(w0) | ((u64)f2bf(w1) << 16) | ((u64)f2bf(w2) << 32) |
          ((u64)f2bf(w3) << 48);
  if (!valid) W = 0;
  const int s = c * 16 - 48;  // bit offset of t=c-3 in the 128-bit [t0..t7] field
  if (s < 0)       { lo = W >> (-s); hi = 0; }
  else if (s == 0) { lo = W;         hi = 0; }
  else if (s < 64) { lo = W << s;    hi = W >> (64 - s); }
  else             { lo = 0;         hi = W << (s - 64); }
}

// Wc[o][k] bf16: k<512 -> base_weight; else spline_weight*scaler (k = 512 + i*8 + t)
__global__ __launch_bounds__(256) void kan_prep(const float* __restrict__ bw,
                                                const float* __restrict__ sw,
                                                const float* __restrict__ ss,
                                                u16* __restrict__ Wc) {
  const int t = blockIdx.x * 256 + threadIdx.x;  // 0..262143 = o*512 + i
  const int o = t >> 9, i = t & 511;
  const float s = ss[t];
  const float* sp = sw + (size_t)t * 8;
  f32x4 s0 = *(const f32x4*)sp;
  f32x4 s1 = *(const f32x4*)(sp + 4);
  u16x8 p;
#pragma unroll
  for (int e = 0; e < 4; ++e) {
    p[e] = f2bf(s0[e] * s);
    p[4 + e] = f2bf(s1[e] * s);
  }
  *(u16x8*)&Wc[(size_t)o * KTOT + IN_F + i * 8] = p;
  Wc[(size_t)o * KTOT + i] = f2bf(bw[t]);
}

__global__ __launch_bounds__(256, 1) void kan_gemm(const float* __restrict__ x,
                                                   const u16* __restrict__ Wc,
                                                   float* __restrict__ out) {
  __shared__ u16 As[BM * LDSS];
  __shared__ u16 Bs[BN * LDSS];
  const int tid = threadIdx.x;
  const int b = blockIdx.x;
  const int n0 = (b & 1) * BN;    // parity swizzle: each XCD sees one Wc half
  const int m0 = (b >> 1) * BM;

  const int lane = tid & 63;
  const int wv = tid >> 6;        // wave 0..3, owns 128x64 output
  const int lr = lane & 15;
  const int lk = lane >> 4;       // 0..3

  const int rB = tid >> 1;        // B stage rows rB, rB+128
  const int segB = (tid & 1) * 32;
  const int rA = tid >> 1;        // A stage row
  const int xch = tid & 1;        // spline xcol half (4 cols each)
  const int hcA = (tid & 1) * 32; // silu col half

  f32x4 acc[8][4];
  const f32x4 zero = {0.0f, 0.0f, 0.0f, 0.0f};
#pragma unroll
  for (int m = 0; m < 8; ++m)
#pragma unroll
    for (int n = 0; n < 4; ++n) acc[m][n] = zero;

  const u16* bsrc0 = Wc + (size_t)(n0 + rB) * KTOT + segB;
  const u16* bsrc1 = bsrc0 + (size_t)128 * KTOT;
  const float* xrow = x + (size_t)(m0 + rA) * IN_F;

  u16x8 br[8];   // B tile prefetch (one kt ahead)
  u16x8 aw[4];   // spline A fragments (computed one kt ahead, during MFMA)

  // prologue: prefetch B for kt=0
#pragma unroll
  for (int q = 0; q < 4; ++q) br[q] = *(const u16x8*)(bsrc0 + q * 8);
#pragma unroll
  for (int q = 0; q < 4; ++q) br[4 + q] = *(const u16x8*)(bsrc1 + q * 8);

  for (int kt = 0; kt < NKT; ++kt) {
    const int k0 = kt * BK;
    __syncthreads();
    // ---- write B tile
#pragma unroll
    for (int q = 0; q < 8; ++q)
      *(u16x8*)&Bs[(rB + (q >> 2) * 128) * LDSS + segB + (q & 3) * 8] = br[q];
    // ---- write A tile
    if (kt < NSIL) {
      const float* xs = xrow + k0 + hcA;
#pragma unroll
      for (int q = 0; q < 4; ++q) {
        f32x4 a0 = *(const f32x4*)(xs + q * 8);
        f32x4 a1 = *(const f32x4*)(xs + q * 8 + 4);
        u16x8 p;
#pragma unroll
        for (int e = 0; e < 4; ++e) {
          p[e] = f2bf(siluf(a0[e]));
          p[4 + e] = f2bf(siluf(a1[e]));
        }
        *(u16x8*)&As[rA * LDSS + hcA + q * 8] = p;
      }
    } else {
#pragma unroll
      for (int e = 0; e < 4; ++e)
        *(u16x8*)&As[rA * LDSS + (xch * 4 + e) * 8] = aw[e];
    }
    __syncthreads();
    // ---- MFMA: wave tile 128x64, two K=32 substeps
#pragma unroll
    for (int s = 0; s < 2; ++s) {
      bf16x8 af[8], bfr[4];
#pragma unroll
      for (int m = 0; m < 8; ++m)
        af[m] = *(const bf16x8*)&As[(m * 16 + lr) * LDSS + s * 32 + lk * 8];
#pragma unroll
      for (int n = 0; n < 4; ++n)
        bfr[n] = *(const bf16x8*)&Bs[(wv * 64 + n * 16 + lr) * LDSS + s * 32 + lk * 8];
#pragma unroll
      for (int m = 0; m < 8; ++m)
#pragma unroll
        for (int n = 0; n < 4; ++n)
          acc[m][n] = __builtin_amdgcn_mfma_f32_16x16x32_bf16(af[m], bfr[n], acc[m][n], 0, 0, 0);
    }
    // ---- tail: prefetch kt+1 (B loads + spline A compute overlap MFMA drain)
    const int kn = kt + 1;
    if (kn < NKT) {
      const u16* p0 = bsrc0 + kn * BK;
      const u16* p1 = bsrc1 + kn * BK;
#pragma unroll
      for (int q = 0; q < 4; ++q) br[q] = *(const u16x8*)(p0 + q * 8);
#pragma unroll
      for (int q = 0; q < 4; ++q) br[4 + q] = *(const u16x8*)(p1 + q * 8);
      if (kn >= NSIL) {
        const int i0 = kn * 8 - 64;  // (kn*64 - 512)/8
        f32x4 xv = *(const f32x4*)(xrow + i0 + xch * 4);
#pragma unroll
        for (int e = 0; e < 4; ++e) {
          u64 lo, hi;
          spline8(xv[e], lo, hi);
          union { struct { u64 a, b; } q; u16x8 v; } uu;
          uu.q.a = lo; uu.q.b = hi;
          aw[e] = uu.v;
        }
      }
    }
  }

  // epilogue: C/D layout col=lane&15, row=(lane>>4)*4+j
#pragma unroll
  for (int m = 0; m < 8; ++m)
#pragma unroll
    for (int n = 0; n < 4; ++n)
#pragma unroll
      for (int j = 0; j < 4; ++j)
        out[(size_t)(m0 + m * 16 + lk * 4 + j) * OUT_F + n0 + wv * 64 + n * 16 + lr] =
            acc[m][n][j];
}

extern "C" void kernel_launch(void* const* d_in, const int* in_sizes, int n_in,
                              void* d_out, int out_size, void* d_ws, size_t ws_size,
                              hipStream_t stream) {
  const float* x  = (const float*)d_in[0];
  const float* bw = (const float*)d_in[1];
  const float* sw = (const float*)d_in[2];
  const float* ss = (const float*)d_in[3];
  u16* Wc = (u16*)d_ws;  // 512*4608*2 = 4.72 MB

  kan_prep<<<dim3(OUT_F * IN_F / 256), 256, 0, stream>>>(bw, sw, ss, Wc);
  kan_gemm<<<dim3((16384 / BM) * (OUT_F / BN)), 256, 0, stream>>>(
      x, Wc, (float*)d_out);
}